// Round 3
// baseline (172.378 us; speedup 1.0000x reference)
//
#include <hip/hip_runtime.h>
#include <hip/hip_bf16.h>

#define NB 32
#define NT 1024
#define ND 256
#define ETA 0.1f
#define INVS 0.70710678118654752440f

typedef short bf16x8 __attribute__((ext_vector_type(8)));
typedef float f32x4  __attribute__((ext_vector_type(4)));

__device__ inline unsigned short f2bf(float f){
  __hip_bfloat16 h = __float2bfloat16(f);
  return *reinterpret_cast<unsigned short*>(&h);
}
__device__ inline float bf2f(unsigned short u){
  return __uint_as_float(((unsigned int)u) << 16);
}

// ---- in-register Haar primitives (all indices compile-time after unroll) ----
// IDWT level: a[0..N) approx + d[0..N) details -> a[0..2N) interleaved (in-place, descending-safe)
template<int N>
__device__ inline void idwt_lvl(float* a, const float* d){
#pragma unroll
  for (int i = N-1; i >= 0; --i){
    float av = a[i], dv = d[i];
    a[2*i]   = (av + dv) * INVS;
    a[2*i+1] = (av - dv) * INVS;
  }
}
// DWT level: a[0..2N) -> a[0..N) approx, d[0..N) details (in-place, ascending-safe)
template<int N>
__device__ inline void dwt_lvl(float* a, float* d){
#pragma unroll
  for (int i = 0; i < N; ++i){
    float e = a[2*i], o = a[2*i+1];
    a[i] = (e + o) * INVS;
    d[i] = (e - o) * INVS;
  }
}

// ---------------- coarse kernels: 6 levels over coeff rows 0..63, one column per thread ----------------
// first: c rows0..63 = w*rho (store), A4 = coarse-IDWT(c rows0..63)
__global__ __launch_bounds__(256) void k_coarse_first(const float* __restrict__ rho,
                                                      const float* __restrict__ w,
                                                      float* __restrict__ c,
                                                      float* __restrict__ A4){
  int g = blockIdx.x * 256 + threadIdx.x;       // 32 blocks: g = b*256 + d
  int b = g >> 8, d = g & 255;
  size_t cb = ((size_t)b * NT) * ND + d;
  float x[64];
#pragma unroll
  for (int r = 0; r < 64; ++r){
    size_t o = (size_t)r * ND;
    float v = rho[cb + o] * w[o + d];
    c[cb + o] = v;
    x[r] = v;
  }
  float a[64];
  a[0] = x[0];
  idwt_lvl<1>(a, x+1);  idwt_lvl<2>(a, x+2);   idwt_lvl<4>(a, x+4);
  idwt_lvl<8>(a, x+8);  idwt_lvl<16>(a, x+16); idwt_lvl<32>(a, x+32);
  size_t ab = ((size_t)b * 64) * ND + d;
#pragma unroll
  for (int j = 0; j < 64; ++j) A4[ab + (size_t)j*ND] = a[j];
}

// mid: C2coarse = coarse-DWT(a4p); blend with c rows0..63 (store c'); A4n = coarse-IDWT(c')
__global__ __launch_bounds__(256) void k_coarse_mid(const float* __restrict__ a4p,
                                                    float* __restrict__ c,
                                                    float* __restrict__ A4n){
  int g = blockIdx.x * 256 + threadIdx.x;
  int b = g >> 8, d = g & 255;
  size_t ab = ((size_t)b * 64) * ND + d;
  float x[64];
#pragma unroll
  for (int j = 0; j < 64; ++j) x[j] = a4p[ab + (size_t)j*ND];
  float y[64];
  dwt_lvl<32>(x, y+32); dwt_lvl<16>(x, y+16); dwt_lvl<8>(x, y+8);
  dwt_lvl<4>(x, y+4);   dwt_lvl<2>(x, y+2);   dwt_lvl<1>(x, y+1);
  y[0] = x[0];
  size_t cb = ((size_t)b * NT) * ND + d;
  float nc[64];
#pragma unroll
  for (int r = 0; r < 64; ++r){
    size_t o = (size_t)r * ND;
    float cv = c[cb + o];
    float nv = cv - ETA * (cv - y[r]);
    c[cb + o] = nv;
    nc[r] = nv;
  }
  float a[64];
  a[0] = nc[0];
  idwt_lvl<1>(a, nc+1);  idwt_lvl<2>(a, nc+2);   idwt_lvl<4>(a, nc+4);
  idwt_lvl<8>(a, nc+8);  idwt_lvl<16>(a, nc+16); idwt_lvl<32>(a, nc+32);
#pragma unroll
  for (int j = 0; j < 64; ++j) A4n[ab + (size_t)j*ND] = a[j];
}

// final: C2coarse = coarse-DWT(a4p); out rows0..63 = blend(c',C2)/w
__global__ __launch_bounds__(256) void k_coarse_final(const float* __restrict__ a4p,
                                                      float* __restrict__ c,
                                                      const float* __restrict__ w){
  int g = blockIdx.x * 256 + threadIdx.x;
  int b = g >> 8, d = g & 255;
  size_t ab = ((size_t)b * 64) * ND + d;
  float x[64];
#pragma unroll
  for (int j = 0; j < 64; ++j) x[j] = a4p[ab + (size_t)j*ND];
  float y[64];
  dwt_lvl<32>(x, y+32); dwt_lvl<16>(x, y+16); dwt_lvl<8>(x, y+8);
  dwt_lvl<4>(x, y+4);   dwt_lvl<2>(x, y+2);   dwt_lvl<1>(x, y+1);
  y[0] = x[0];
  size_t cb = ((size_t)b * NT) * ND + d;
#pragma unroll
  for (int r = 0; r < 64; ++r){
    size_t o = (size_t)r * ND;
    float cv = c[cb + o];
    c[cb + o] = (cv - ETA * (cv - y[r])) / w[o + d];
  }
}

// ---------------- fine kernels: 4 levels within a 16-row chunk, one (b,j,d) per thread ----------------
// first: c fine rows = w*rho (store); S chunk = fine-IDWT(A4[j], fine coeffs)
__global__ __launch_bounds__(256) void k_fine_first(const float* __restrict__ rho,
                                                    const float* __restrict__ w,
                                                    const float* __restrict__ A4,
                                                    float* __restrict__ c,
                                                    unsigned short* __restrict__ S){
  int bx = blockIdx.x;                 // b*64 + j
  int b = bx >> 6, j = bx & 63;
  int d = threadIdx.x;
  size_t cb = ((size_t)b * NT) * ND + d;
  float a[16], d1[8], d2[4], d3[2], d4;
  {
    size_t o = (size_t)(64 + j) * ND;
    float v = rho[cb + o] * w[o + d];  c[cb + o] = v;  d4 = v;
  }
#pragma unroll
  for (int i = 0; i < 2; ++i){
    size_t o = (size_t)(128 + 2*j + i) * ND;
    float v = rho[cb + o] * w[o + d];  c[cb + o] = v;  d3[i] = v;
  }
#pragma unroll
  for (int i = 0; i < 4; ++i){
    size_t o = (size_t)(256 + 4*j + i) * ND;
    float v = rho[cb + o] * w[o + d];  c[cb + o] = v;  d2[i] = v;
  }
#pragma unroll
  for (int i = 0; i < 8; ++i){
    size_t o = (size_t)(512 + 8*j + i) * ND;
    float v = rho[cb + o] * w[o + d];  c[cb + o] = v;  d1[i] = v;
  }
  a[0] = A4[(((size_t)b * 64) + j) * ND + d];
  idwt_lvl<1>(a, &d4); idwt_lvl<2>(a, d3); idwt_lvl<4>(a, d2); idwt_lvl<8>(a, d1);
#pragma unroll
  for (int i = 0; i < 16; ++i) S[cb + (size_t)(16*j + i) * ND] = f2bf(a[i]);
}

// mid: fine-DWT(Y chunk) -> blend fine coeff rows of c (store c'); a4p[j] = chunk approx (unblended)
__global__ __launch_bounds__(256) void k_fine_dwt_mid(const unsigned short* __restrict__ Y,
                                                      float* __restrict__ c,
                                                      float* __restrict__ a4p){
  int bx = blockIdx.x;
  int b = bx >> 6, j = bx & 63;
  int d = threadIdx.x;
  size_t cb = ((size_t)b * NT) * ND + d;
  float x[16];
#pragma unroll
  for (int i = 0; i < 16; ++i) x[i] = bf2f(Y[cb + (size_t)(16*j + i) * ND]);
  float d1[8], d2[4], d3[2], d4;
  dwt_lvl<8>(x, d1); dwt_lvl<4>(x, d2); dwt_lvl<2>(x, d3); dwt_lvl<1>(x, &d4);
  a4p[(((size_t)b * 64) + j) * ND + d] = x[0];
  {
    size_t o = (size_t)(64 + j) * ND;
    float cv = c[cb + o]; c[cb + o] = cv - ETA * (cv - d4);
  }
#pragma unroll
  for (int i = 0; i < 2; ++i){
    size_t o = (size_t)(128 + 2*j + i) * ND;
    float cv = c[cb + o]; c[cb + o] = cv - ETA * (cv - d3[i]);
  }
#pragma unroll
  for (int i = 0; i < 4; ++i){
    size_t o = (size_t)(256 + 4*j + i) * ND;
    float cv = c[cb + o]; c[cb + o] = cv - ETA * (cv - d2[i]);
  }
#pragma unroll
  for (int i = 0; i < 8; ++i){
    size_t o = (size_t)(512 + 8*j + i) * ND;
    float cv = c[cb + o]; c[cb + o] = cv - ETA * (cv - d1[i]);
  }
}

// mid: S chunk = fine-IDWT(A4n[j], c' fine rows)
__global__ __launch_bounds__(256) void k_fine_idwt_mid(const float* __restrict__ c,
                                                       const float* __restrict__ A4n,
                                                       unsigned short* __restrict__ S){
  int bx = blockIdx.x;
  int b = bx >> 6, j = bx & 63;
  int d = threadIdx.x;
  size_t cb = ((size_t)b * NT) * ND + d;
  float a[16], d1[8], d2[4], d3[2], d4;
  d4 = c[cb + (size_t)(64 + j) * ND];
#pragma unroll
  for (int i = 0; i < 2; ++i) d3[i] = c[cb + (size_t)(128 + 2*j + i) * ND];
#pragma unroll
  for (int i = 0; i < 4; ++i) d2[i] = c[cb + (size_t)(256 + 4*j + i) * ND];
#pragma unroll
  for (int i = 0; i < 8; ++i) d1[i] = c[cb + (size_t)(512 + 8*j + i) * ND];
  a[0] = A4n[(((size_t)b * 64) + j) * ND + d];
  idwt_lvl<1>(a, &d4); idwt_lvl<2>(a, d3); idwt_lvl<4>(a, d2); idwt_lvl<8>(a, d1);
#pragma unroll
  for (int i = 0; i < 16; ++i) S[cb + (size_t)(16*j + i) * ND] = f2bf(a[i]);
}

// final: fine-DWT(Y chunk) -> out fine rows = blend(c',C2)/w; a4p[j] = chunk approx
__global__ __launch_bounds__(256) void k_fine_dwt_final(const unsigned short* __restrict__ Y,
                                                        float* __restrict__ c,
                                                        const float* __restrict__ w,
                                                        float* __restrict__ a4p){
  int bx = blockIdx.x;
  int b = bx >> 6, j = bx & 63;
  int d = threadIdx.x;
  size_t cb = ((size_t)b * NT) * ND + d;
  float x[16];
#pragma unroll
  for (int i = 0; i < 16; ++i) x[i] = bf2f(Y[cb + (size_t)(16*j + i) * ND]);
  float d1[8], d2[4], d3[2], d4;
  dwt_lvl<8>(x, d1); dwt_lvl<4>(x, d2); dwt_lvl<2>(x, d3); dwt_lvl<1>(x, &d4);
  a4p[(((size_t)b * 64) + j) * ND + d] = x[0];
  {
    size_t o = (size_t)(64 + j) * ND;
    float cv = c[cb + o]; c[cb + o] = (cv - ETA * (cv - d4)) / w[o + d];
  }
#pragma unroll
  for (int i = 0; i < 2; ++i){
    size_t o = (size_t)(128 + 2*j + i) * ND;
    float cv = c[cb + o]; c[cb + o] = (cv - ETA * (cv - d3[i])) / w[o + d];
  }
#pragma unroll
  for (int i = 0; i < 4; ++i){
    size_t o = (size_t)(256 + 4*j + i) * ND;
    float cv = c[cb + o]; c[cb + o] = (cv - ETA * (cv - d2[i])) / w[o + d];
  }
#pragma unroll
  for (int i = 0; i < 8; ++i){
    size_t o = (size_t)(512 + 8*j + i) * ND;
    float cv = c[cb + o]; c[cb + o] = (cv - ETA * (cv - d1[i])) / w[o + d];
  }
}

// ---------------- per-band GEMM, register-held B panel, TM=2 tiles/block ----------------
__global__ __launch_bounds__(256, 2) void k_band_gemm(const unsigned short* __restrict__ S,
                                                      const unsigned short* __restrict__ Wt,
                                                      const float* __restrict__ bias,
                                                      unsigned short* __restrict__ Y){
  int bx = blockIdx.x;  // 0..591
  int wv = threadIdx.x >> 6, lane = threadIdx.x & 63;
  int row = lane & 15, kg = lane >> 4;
  int band, jbase; bool masked = false;
  if      (bx <  16){ band =  6; jbase = bx*2; }
  else if (bx <  48){ band =  7; jbase = (bx-16)*2; }
  else if (bx < 112){ band =  8; jbase = (bx-48)*2; }
  else if (bx < 240){ band =  9; jbase = (bx-112)*2; }
  else if (bx < 496){ band = 10; jbase = (bx-240)*2; }
  else { masked = true; int mb = bx-496; band = mb>>4; jbase = (mb&15)*2; }

  int n0 = wv * 64;
  const unsigned short* Wb = Wt + (size_t)band * 65536;

  bf16x8 breg[8][4];
#pragma unroll
  for (int kk = 0; kk < 8; ++kk)
#pragma unroll
    for (int ni = 0; ni < 4; ++ni)
      breg[kk][ni] = *(const bf16x8*)(Wb + (size_t)(n0 + 16*ni + row)*256 + kk*32 + kg*8);

  float bv[4];
#pragma unroll
  for (int ni = 0; ni < 4; ++ni) bv[ni] = bias[band*256 + n0 + 16*ni + row];

  int lo = 0, hi = 0;
  if (masked){
    lo = (band == 0) ? 0 : (1 << (band - 1));
    hi = (band == 0) ? 1 : (1 << band);
  }
  int shift = masked ? 0 : (band - 6);
  int tstart = masked ? 0 : (32 << shift);

  for (int m = 0; m < 2; ++m){
    int j = jbase + m;
    int bb, t0;
    if (masked){ bb = j; t0 = 0; }
    else { bb = j >> shift; t0 = tstart + (j & ((1 << shift) - 1)) * 32; }

    f32x4 acc[2][4];
#pragma unroll
    for (int mi = 0; mi < 2; ++mi)
#pragma unroll
      for (int ni = 0; ni < 4; ++ni) acc[mi][ni] = (f32x4){0.f, 0.f, 0.f, 0.f};

    size_t arow0 = ((size_t)bb * NT + t0 + row) * ND;
#pragma unroll
    for (int kk = 0; kk < 8; ++kk){
      int k = kk*32 + kg*8;
      bf16x8 a0 = *(const bf16x8*)(S + arow0 + k);
      bf16x8 a1 = *(const bf16x8*)(S + arow0 + 16*ND + k);
#pragma unroll
      for (int ni = 0; ni < 4; ++ni){
        acc[0][ni] = __builtin_amdgcn_mfma_f32_16x16x32_bf16(a0, breg[kk][ni], acc[0][ni], 0, 0, 0);
        acc[1][ni] = __builtin_amdgcn_mfma_f32_16x16x32_bf16(a1, breg[kk][ni], acc[1][ni], 0, 0, 0);
      }
    }
#pragma unroll
    for (int ni = 0; ni < 4; ++ni){
#pragma unroll
      for (int mi = 0; mi < 2; ++mi){
#pragma unroll
        for (int jj = 0; jj < 4; ++jj){
          int t = t0 + 16*mi + kg*4 + jj;   // C/D: row=(lane>>4)*4+reg, col=lane&15
          if (!masked || (t >= lo && t < hi)){
            Y[((size_t)bb*NT + t)*ND + n0 + 16*ni + row] = f2bf(acc[mi][ni][jj] + bv[ni]);
          }
        }
      }
    }
  }
}

// ---------------- Wt[band][e][d] = bf16(W[band][d][e]) ----------------
__global__ __launch_bounds__(256) void k_wprep(const float* __restrict__ W,
                                               unsigned short* __restrict__ Wt){
  __shared__ float tbuf[32][33];
  int band = blockIdx.y;
  int tile = blockIdx.x;             // 0..63 -> 8x8 grid of 32x32 tiles
  int td0 = (tile >> 3) * 32, te0 = (tile & 7) * 32;
  int tx = threadIdx.x & 31, ty = threadIdx.x >> 5;
#pragma unroll
  for (int i = 0; i < 4; ++i){
    tbuf[ty*4 + i][tx] = W[(size_t)band*65536 + (size_t)(td0 + ty*4 + i)*256 + te0 + tx];
  }
  __syncthreads();
#pragma unroll
  for (int i = 0; i < 4; ++i){
    Wt[(size_t)band*65536 + (size_t)(te0 + ty*4 + i)*256 + td0 + tx] = f2bf(tbuf[tx][ty*4 + i]);
  }
}

extern "C" void kernel_launch(void* const* d_in, const int* in_sizes, int n_in,
                              void* d_out, int out_size, void* d_ws, size_t ws_size,
                              hipStream_t stream){
  const float* rho  = (const float*)d_in[0];
  const float* w    = (const float*)d_in[1];
  const float* W    = (const float*)d_in[2];
  const float* bias = (const float*)d_in[3];

  float* c = (float*)d_out;                                   // coeff state lives in d_out
  unsigned short* S  = (unsigned short*)d_ws;                 // 16 MB bf16 signal
  unsigned short* Y  = S + (size_t)NB * NT * ND;              // 16 MB bf16 predicted signal
  unsigned short* Wt = Y + (size_t)NB * NT * ND;              // 1.4 MB bf16 transposed weights
  // 2 MB coarse scratch buffers alias dead buffer heads (lifetimes verified):
  float* P0 = (float*)Y;   // A4 (live coarse_first->fine_first), A4' (coarse_mid->fine_idwt_mid)
  float* P1 = (float*)S;   // a4p (fine_dwt_mid->coarse_mid), a4p2 (fine_dwt_final->coarse_final)

  k_wprep<<<dim3(64, 11), 256, 0, stream>>>(W, Wt);
  k_coarse_first<<<32, 256, 0, stream>>>(rho, w, c, P0);
  k_fine_first<<<NB*64, 256, 0, stream>>>(rho, w, P0, c, S);
  k_band_gemm<<<592, 256, 0, stream>>>(S, Wt, bias, Y);
  k_fine_dwt_mid<<<NB*64, 256, 0, stream>>>(Y, c, P1);
  k_coarse_mid<<<32, 256, 0, stream>>>(P1, c, P0);
  k_fine_idwt_mid<<<NB*64, 256, 0, stream>>>(c, P0, S);
  k_band_gemm<<<592, 256, 0, stream>>>(S, Wt, bias, Y);
  k_fine_dwt_final<<<NB*64, 256, 0, stream>>>(Y, c, w, P1);
  k_coarse_final<<<32, 256, 0, stream>>>(P1, c, w);
}